// Round 3
// baseline (12608.234 us; speedup 1.0000x reference)
//
#include <hip/hip_runtime.h>
#include <hip/hip_bf16.h>

// ---------------------------------------------------------------------------
// up_deeplabv3Head — round 2: runtime dtype-adaptive (fp32 OR bf16 storage).
// A probe kernel classifies the input storage format once per launch (same
// result every launch -> graph-safe); all input loads / output store branch
// on the wave-uniform flag. Intermediates are fp32 in d_ws (~6.8 MB).
// Algebraic fusions (unchanged from round 1):
//   * c6 1x1 commutes with attention-agg and resize -> 19-ch tail
//   * ap 1x1 over concat = sum of per-segment 1x1 GEMMs (no fcat buffer)
//   * GAP branch -> per-channel constant folded into aspp BN
//   * dilation-36 conv == center tap only; r2 1x1 commutes with resize
// ---------------------------------------------------------------------------

typedef unsigned short u16;

__device__ __forceinline__ float bf2f(u16 u) {
    return __uint_as_float(((unsigned int)u) << 16);
}
// flag f32: 1 -> storage fp32, 0 -> storage bf16
__device__ __forceinline__ float loadv(const void* p, long i, int f32) {
    return f32 ? ((const float*)p)[i] : bf2f(((const u16*)p)[i]);
}

// ---------------------------------------------------------------------------
// dtype probe: count u16 words of c1 whose bf16 exponent field >= 2^31.
// bf16-stored N(0,1): ~0 hits. fp32-stored: ~38% of even words hit.
// ---------------------------------------------------------------------------
__global__ __launch_bounds__(256) void detect_kernel(
    const u16* __restrict__ c1, int* __restrict__ flag)
{
    __shared__ int cnt;
    if (threadIdx.x == 0) cnt = 0;
    __syncthreads();
    int local = 0;
    for (int i = threadIdx.x; i < 16384; i += 256) {
        u16 u = c1[i];
        if ((u & 0x7F80) >= 0x4F00) local++;
    }
    atomicAdd(&cnt, local);
    __syncthreads();
    if (threadIdx.x == 0) flag[0] = (cnt > 256) ? 1 : 0;
}

// ---------------------------------------------------------------------------
// Tap-GEMM: OUT[o, out_p] (+)= sum_k W[o*wrow + woff + k*wstride] * X[k, in_p]
// W is an external input (dtype per flag). X external (x_ext=1, dtype per
// flag) or ws fp32 (x_ext=0). Block: 64 o x 64 px, 256 thr, 4x4 microtile.
// ---------------------------------------------------------------------------
__global__ __launch_bounds__(256) void gemm_tap(
    const void* __restrict__ W, const void* __restrict__ X, float* __restrict__ OUT,
    const int* __restrict__ flag, int x_ext,
    int K, int wrow, int wstride, int woff, int IW, int NP,
    int y0, int x0, int ny, int nx, int dy, int dx, int accumulate)
{
    __shared__ float Ws[16][64];
    __shared__ float Xs[16][64];
    __shared__ int inp_tab[64];
    __shared__ int outp_tab[64];

    const int wf32 = flag[0];
    const int xf32 = x_ext ? wf32 : 1;

    const int tid = threadIdx.x;
    const int bo = blockIdx.x, bp = blockIdx.y;

    if (tid < 64) {
        int r = bp * 64 + tid;
        int inp = 0, outp = -1;
        if (r < ny * nx) {
            int ry = r / nx, rx = r - ry * nx;
            int y = y0 + ry, x = x0 + rx;
            outp = y * IW + x;
            inp  = (y + dy) * IW + (x + dx);
        }
        inp_tab[tid] = inp;
        outp_tab[tid] = outp;
    }
    __syncthreads();

    const int ty = tid >> 4, tx = tid & 15;
    float acc[4][4];
#pragma unroll
    for (int i = 0; i < 4; i++)
#pragma unroll
        for (int j = 0; j < 4; j++) acc[i][j] = 0.f;

    const int w_o  = tid >> 2;        // 0..63
    const int w_kg = (tid & 3) * 4;   // 0,4,8,12
    const int x_kk = tid >> 4;        // 0..15
    const int x_pg = (tid & 15) * 4;  // 0..60
    const int ip0 = inp_tab[x_pg + 0], ip1 = inp_tab[x_pg + 1];
    const int ip2 = inp_tab[x_pg + 2], ip3 = inp_tab[x_pg + 3];

    const long wbase = (long)(bo * 64 + w_o) * (long)wrow + woff;

    for (int k0 = 0; k0 < K; k0 += 16) {
        // ---- stage W (16 k x 64 o) ----
        if (wstride == 1) {
            long idx = wbase + k0 + w_kg;
            if (wf32) {
                float4 v = *(const float4*)((const float*)W + idx);
                Ws[w_kg + 0][w_o] = v.x; Ws[w_kg + 1][w_o] = v.y;
                Ws[w_kg + 2][w_o] = v.z; Ws[w_kg + 3][w_o] = v.w;
            } else {
                ushort4 v = *(const ushort4*)((const u16*)W + idx);
                Ws[w_kg + 0][w_o] = bf2f(v.x); Ws[w_kg + 1][w_o] = bf2f(v.y);
                Ws[w_kg + 2][w_o] = bf2f(v.z); Ws[w_kg + 3][w_o] = bf2f(v.w);
            }
        } else {
            long idx = wbase + (long)(k0 + w_kg) * wstride;
#pragma unroll
            for (int j = 0; j < 4; j++)
                Ws[w_kg + j][w_o] = loadv(W, idx + (long)j * wstride, wf32);
        }
        // ---- stage X (16 k x 64 px) ----
        {
            long xb = (long)(k0 + x_kk) * NP;
            Xs[x_kk][x_pg + 0] = loadv(X, xb + ip0, xf32);
            Xs[x_kk][x_pg + 1] = loadv(X, xb + ip1, xf32);
            Xs[x_kk][x_pg + 2] = loadv(X, xb + ip2, xf32);
            Xs[x_kk][x_pg + 3] = loadv(X, xb + ip3, xf32);
        }
        __syncthreads();
#pragma unroll
        for (int kk = 0; kk < 16; kk++) {
            const float4 wv = *(const float4*)(&Ws[kk][ty * 4]);
            const float4 xv = *(const float4*)(&Xs[kk][tx * 4]);
            float wa[4] = {wv.x, wv.y, wv.z, wv.w};
            float xa[4] = {xv.x, xv.y, xv.z, xv.w};
#pragma unroll
            for (int i = 0; i < 4; i++)
#pragma unroll
                for (int j = 0; j < 4; j++)
                    acc[i][j] = fmaf(wa[i], xa[j], acc[i][j]);
        }
        __syncthreads();
    }

#pragma unroll
    for (int j = 0; j < 4; j++) {
        int op = outp_tab[tx * 4 + j];
        if (op >= 0) {
#pragma unroll
            for (int i = 0; i < 4; i++) {
                float* dst = OUT + (long)(bo * 64 + ty * 4 + i) * NP + op;
                if (accumulate) *dst += acc[i][j];
                else            *dst  = acc[i][j];
            }
        }
    }
}

// bn+relu in place over (C, N) f32, N = 2^logN; s,b external
__global__ __launch_bounds__(256) void ep_bnrelu(
    float* __restrict__ buf, const void* __restrict__ s, const void* __restrict__ b,
    const int* __restrict__ flag, int logN, int total)
{
    int f32 = flag[0];
    int g = blockIdx.x * 256 + threadIdx.x;
    if (g >= total) return;
    int c = g >> logN;
    float v = buf[g] * loadv(s, c, f32) + loadv(b, c, f32);
    buf[g] = fmaxf(v, 0.f);
}

// aspp epilogue: v = relu((acc + f4con[c]) * s[c] + b[c]); (512,1024)
__global__ __launch_bounds__(256) void ep_aspp(
    float* __restrict__ buf, const float* __restrict__ f4con,
    const void* __restrict__ s, const void* __restrict__ b, const int* __restrict__ flag)
{
    int f32 = flag[0];
    int g = blockIdx.x * 256 + threadIdx.x;  // 524288 exact
    int c = g >> 10;
    float v = (buf[g] + f4con[c]) * loadv(s, c, f32) + loadv(b, c, f32);
    buf[g] = fmaxf(v, 0.f);
}

// bilinear resize 32x32 -> 64x64 align_corners, optional bn+relu, (C,*) fp32 in
__global__ __launch_bounds__(256) void resize_bn(
    const float* __restrict__ in, float* __restrict__ out,
    const void* __restrict__ s, const void* __restrict__ b,
    const int* __restrict__ flag, int dobn)
{
    int g = blockIdx.x * 256 + threadIdx.x;  // C*4096 exact
    int c = g >> 12, p = g & 4095;
    int oy = p >> 6, ox = p & 63;
    const float r = 31.0f / 63.0f;
    float tyf = oy * r, txf = ox * r;
    int y0 = (int)tyf, x0 = (int)txf;
    float fy = tyf - y0, fx = txf - x0;
    int y1 = y0 + 1 > 31 ? 31 : y0 + 1;
    int x1 = x0 + 1 > 31 ? 31 : x0 + 1;
    const float* pc = in + c * 1024;
    float v00 = pc[y0 * 32 + x0], v01 = pc[y0 * 32 + x1];
    float v10 = pc[y1 * 32 + x0], v11 = pc[y1 * 32 + x1];
    float v = (1.f - fy) * ((1.f - fx) * v00 + fx * v01) +
              fy * ((1.f - fx) * v10 + fx * v11);
    if (dobn) v = fmaxf(v * loadv(s, c, flag[0]) + loadv(b, c, flag[0]), 0.f);
    out[g] = v;
}

// energy + softmax: one wave (64 lanes = 64 channels) per pixel of 64x64
__global__ __launch_bounds__(256) void attn_kernel(
    const float* __restrict__ c1r, const float* __restrict__ c2r, float* __restrict__ att)
{
    int tid = threadIdx.x;
    int p = blockIdx.x * 4 + (tid >> 6);
    int lane = tid & 63;
    int y = p >> 6, x = p & 63;
    float a = c1r[lane * 4096 + p];
    float e[9];
#pragma unroll
    for (int ky = 0; ky < 3; ky++)
#pragma unroll
        for (int kx = 0; kx < 3; kx++) {
            int yy = y + 2 * (ky - 1), xx = x + 2 * (kx - 1);
            float v = 0.f;
            if (yy >= 0 && yy < 64 && xx >= 0 && xx < 64)
                v = a * c2r[lane * 4096 + yy * 64 + xx];
#pragma unroll
            for (int off = 32; off; off >>= 1) v += __shfl_xor(v, off);
            e[ky * 3 + kx] = v;
        }
    float m = e[0];
#pragma unroll
    for (int k = 1; k < 9; k++) m = fmaxf(m, e[k]);
    float ssum = 0.f;
#pragma unroll
    for (int k = 0; k < 9; k++) ssum += __expf(e[k] - m);
    if (lane < 9) {
        float mye = e[0];
#pragma unroll
        for (int k = 1; k < 9; k++)
            if (lane == k) mye = e[k];
        att[p * 9 + lane] = __expf(mye - m) / ssum;
    }
}

// global average pool over 1024 px: one wave per channel (4096 channels)
__global__ __launch_bounds__(256) void gap_kernel(
    const void* __restrict__ x, const int* __restrict__ flag, float* __restrict__ gap)
{
    int f32 = flag[0];
    int tid = threadIdx.x;
    int c = blockIdx.x * 4 + (tid >> 6);
    int lane = tid & 63;
    long base = (long)c * 1024;
    float ssum = 0.f;
#pragma unroll
    for (int i = 0; i < 16; i++) ssum += loadv(x, base + lane + i * 64, f32);
#pragma unroll
    for (int off = 32; off; off >>= 1) ssum += __shfl_xor(ssum, off);
    if (lane == 0) gap[c] = ssum * (1.0f / 1024.0f);
}

// f4 channel vector: one wave per output channel (512)
__global__ __launch_bounds__(256) void f4_kernel(
    const void* __restrict__ w, const float* __restrict__ gap,
    const void* __restrict__ s, const void* __restrict__ b,
    const int* __restrict__ flag, float* __restrict__ f4c)
{
    int f32 = flag[0];
    int tid = threadIdx.x;
    int o = blockIdx.x * 4 + (tid >> 6);
    int lane = tid & 63;
    long base = (long)o * 4096;
    float ssum = 0.f;
#pragma unroll
    for (int i = 0; i < 64; i++)
        ssum += loadv(w, base + lane + i * 64, f32) * gap[lane + i * 64];
#pragma unroll
    for (int off = 32; off; off >>= 1) ssum += __shfl_xor(ssum, off);
    if (lane == 0) f4c[o] = fmaxf(ssum * loadv(s, o, f32) + loadv(b, o, f32), 0.f);
}

// f4con[o] = sum_c ap_w[o, 2048 + c] * f4c[c]   (one wave per o, 512 o)
__global__ __launch_bounds__(256) void f4con_kernel(
    const void* __restrict__ ap_w, const float* __restrict__ f4c,
    const int* __restrict__ flag, float* __restrict__ f4con)
{
    int f32 = flag[0];
    int tid = threadIdx.x;
    int o = blockIdx.x * 4 + (tid >> 6);
    int lane = tid & 63;
    long base = (long)o * 2560 + 2048;
    float ssum = 0.f;
#pragma unroll
    for (int i = 0; i < 8; i++)
        ssum += loadv(ap_w, base + lane + i * 64, f32) * f4c[lane + i * 64];
#pragma unroll
    for (int off = 32; off; off >>= 1) ssum += __shfl_xor(ssum, off);
    if (lane == 0) f4con[o] = ssum;
}

// Vs[q,p] = sum_c c6_w[q,c] * aspp[c,p]   (19 x 1024)
__global__ __launch_bounds__(256) void vs_kernel(
    const float* __restrict__ aspp, const void* __restrict__ w,
    const int* __restrict__ flag, float* __restrict__ Vs)
{
    int f32 = flag[0];
    int p = blockIdx.x * 256 + threadIdx.x;  // grid (4, 19)
    int q = blockIdx.y;
    long wb = (long)q * 512;
    float a0 = 0.f, a1 = 0.f, a2 = 0.f, a3 = 0.f;
    for (int c = 0; c < 512; c += 4) {
        a0 = fmaf(loadv(w, wb + c + 0, f32), aspp[(c + 0) * 1024 + p], a0);
        a1 = fmaf(loadv(w, wb + c + 1, f32), aspp[(c + 1) * 1024 + p], a1);
        a2 = fmaf(loadv(w, wb + c + 2, f32), aspp[(c + 2) * 1024 + p], a2);
        a3 = fmaf(loadv(w, wb + c + 3, f32), aspp[(c + 3) * 1024 + p], a3);
    }
    Vs[q * 1024 + p] = (a0 + a1) + (a2 + a3);
}

// out[q,p] = c6_b[q] + sum_k att[p,k] * V[q, nbr_k(p)]; store dtype per flag
__global__ __launch_bounds__(256) void final_kernel(
    const float* __restrict__ att, const float* __restrict__ V,
    const void* __restrict__ bias, const int* __restrict__ flag, void* __restrict__ out)
{
    int f32 = flag[0];
    int g = blockIdx.x * 256 + threadIdx.x;  // 77824 exact (304 blocks)
    int q = g >> 12, p = g & 4095;
    int y = p >> 6, x = p & 63;
    const float* a = att + p * 9;
    const float* v = V + q * 4096;
    float acc = loadv(bias, q, f32);
#pragma unroll
    for (int ky = 0; ky < 3; ky++)
#pragma unroll
        for (int kx = 0; kx < 3; kx++) {
            int yy = y + 2 * (ky - 1), xx = x + 2 * (kx - 1);
            if (yy >= 0 && yy < 64 && xx >= 0 && xx < 64)
                acc += a[ky * 3 + kx] * v[yy * 64 + xx];
        }
    if (f32) ((float*)out)[g] = acc;
    else     ((__hip_bfloat16*)out)[g] = __float2bfloat16(acc);
}

// ---------------------------------------------------------------------------
// Host orchestration
// ---------------------------------------------------------------------------
static void launch_conv(hipStream_t st, const void* X, int x_ext, const void* W,
                        const int* flag, int wrow, int wstride, int woff_base,
                        float* OUT, int O, int K, int IW, int d, int center_accum)
{
    const int NP = IW * IW;
    auto tap = [&](int ky, int kx, int accum) {
        int dy = (ky - 1) * d, dx = (kx - 1) * d;
        int y0 = dy < 0 ? -dy : 0;
        int yend = dy > 0 ? IW - dy : IW;
        int x0 = dx < 0 ? -dx : 0;
        int xend = dx > 0 ? IW - dx : IW;
        int ny = yend - y0, nx = xend - x0;
        if (ny <= 0 || nx <= 0) return;
        int woff = woff_base + ((wstride == 1) ? 0 : (ky * 3 + kx));
        dim3 grid(O / 64, (ny * nx + 63) / 64);
        gemm_tap<<<grid, 256, 0, st>>>(W, X, OUT, flag, x_ext, K, wrow, wstride,
                                       woff, IW, NP, y0, x0, ny, nx, dy, dx, accum);
    };
    tap(1, 1, center_accum);  // center: full rect
    if (d == 0) return;
    for (int ky = 0; ky < 3; ky++)
        for (int kx = 0; kx < 3; kx++)
            if (!(ky == 1 && kx == 1)) tap(ky, kx, 1);
}

extern "C" void kernel_launch(void* const* d_in, const int* in_sizes, int n_in,
                              void* d_out, int out_size, void* d_ws, size_t ws_size,
                              hipStream_t stream)
{
    const void* c1    = d_in[0];   // (256,64,64)
    const void* c2    = d_in[1];   // (512,32,32)
    const void* x     = d_in[2];   // (4096,32,32)
    const void* rf1_w = d_in[3];
    const void* rf1_s = d_in[4];
    const void* rf1_b = d_in[5];
    const void* rf2_w = d_in[6];
    const void* rf2_s = d_in[7];
    const void* rf2_b = d_in[8];
    const void* r2_w  = d_in[9];
    const void* r2_s  = d_in[10];
    const void* r2_b  = d_in[11];
    const void* a0_w  = d_in[12];
    const void* a0_s  = d_in[13];
    const void* a0_b  = d_in[14];
    const void* a1_w  = d_in[15];
    const void* a1_s  = d_in[16];
    const void* a1_b  = d_in[17];
    const void* a2_w  = d_in[18];
    const void* a2_s  = d_in[19];
    const void* a2_b  = d_in[20];
    const void* a3_w  = d_in[21];
    const void* a3_s  = d_in[22];
    const void* a3_b  = d_in[23];
    const void* a4_w  = d_in[24];
    const void* a4_s  = d_in[25];
    const void* a4_b  = d_in[26];
    const void* ap_w  = d_in[27];
    const void* ap_s  = d_in[28];
    const void* ap_b  = d_in[29];
    const void* c6_w  = d_in[30];
    const void* c6_b  = d_in[31];

    // ---- workspace layout (floats), ~6.8 MB + flag ----
    float* ws    = (float*)d_ws;
    float* c1r   = ws;                 //  262144  (64,4096)
    float* c2r   = c1r + 262144;       //  262144  (64,4096)
    float* att   = c2r + 262144;       //   36864  (4096,9)
    float* tmp   = att + 36864;        //  524288  (512,1024); rf1-out uses first half
    float* aspp  = tmp + 524288;       //  524288  (512,1024)
    float* bufC  = aspp + 524288;      //   65536  (64,1024)
    float* gapv  = bufC + 65536;       //    4096
    float* f4c   = gapv + 4096;        //     512
    float* f4con = f4c + 512;          //     512
    float* Vs    = f4con + 512;        //   19456  (19,1024)
    float* V     = Vs + 19456;         //   77824  (19,4096)
    int*   flag  = (int*)(V + 77824);  //       1

    // ---- dtype probe ----
    detect_kernel<<<1, 256, 0, stream>>>((const u16*)c1, flag);

    // ---- refine(c1): two 3x3 dil-2 convs + bn_relu ----
    launch_conv(stream, c1, 1, rf1_w, flag, 256 * 9, 9, 0, tmp, 64, 256, 64, 2, 0);
    ep_bnrelu<<<1024, 256, 0, stream>>>(tmp, rf1_s, rf1_b, flag, 12, 262144);
    launch_conv(stream, tmp, 0, rf2_w, flag, 64 * 9, 9, 0, c1r, 64, 64, 64, 2, 0);
    ep_bnrelu<<<1024, 256, 0, stream>>>(c1r, rf2_s, rf2_b, flag, 12, 262144);

    // ---- refine2: 1x1 conv on c2 (commutes with resize), then resize+bn ----
    launch_conv(stream, c2, 1, r2_w, flag, 512, 1, 0, bufC, 64, 512, 32, 0, 0);
    resize_bn<<<1024, 256, 0, stream>>>(bufC, c2r, r2_s, r2_b, flag, 1);

    // ---- attention (energy + softmax over 9 neighbors) ----
    attn_kernel<<<1024, 256, 0, stream>>>(c1r, c2r, att);

    // ---- GAP branch ----
    gap_kernel<<<1024, 256, 0, stream>>>(x, flag, gapv);
    f4_kernel<<<128, 256, 0, stream>>>(a4_w, gapv, a4_s, a4_b, flag, f4c);
    f4con_kernel<<<128, 256, 0, stream>>>(ap_w, f4c, flag, f4con);

    // ---- ASPP: per-segment conv -> bnrelu -> fold into aspp via ap 1x1 ----
    launch_conv(stream, x, 1, a0_w, flag, 4096, 1, 0, tmp, 512, 4096, 32, 0, 0);
    ep_bnrelu<<<2048, 256, 0, stream>>>(tmp, a0_s, a0_b, flag, 10, 524288);
    launch_conv(stream, tmp, 0, ap_w, flag, 2560, 1, 0, aspp, 512, 512, 32, 0, 0);

    launch_conv(stream, x, 1, a1_w, flag, 4096 * 9, 9, 0, tmp, 512, 4096, 32, 12, 0);
    ep_bnrelu<<<2048, 256, 0, stream>>>(tmp, a1_s, a1_b, flag, 10, 524288);
    launch_conv(stream, tmp, 0, ap_w, flag, 2560, 1, 512, aspp, 512, 512, 32, 0, 1);

    launch_conv(stream, x, 1, a2_w, flag, 4096 * 9, 9, 0, tmp, 512, 4096, 32, 24, 0);
    ep_bnrelu<<<2048, 256, 0, stream>>>(tmp, a2_s, a2_b, flag, 10, 524288);
    launch_conv(stream, tmp, 0, ap_w, flag, 2560, 1, 1024, aspp, 512, 512, 32, 0, 1);

    launch_conv(stream, x, 1, a3_w, flag, 4096 * 9, 9, 0, tmp, 512, 4096, 32, 36, 0);
    ep_bnrelu<<<2048, 256, 0, stream>>>(tmp, a3_s, a3_b, flag, 10, 524288);
    launch_conv(stream, tmp, 0, ap_w, flag, 2560, 1, 1536, aspp, 512, 512, 32, 0, 1);

    ep_aspp<<<2048, 256, 0, stream>>>(aspp, f4con, ap_s, ap_b, flag);

    // ---- tail: c6 on 32x32, resize to 64x64, attention aggregation ----
    vs_kernel<<<dim3(4, 19), 256, 0, stream>>>(aspp, c6_w, flag, Vs);
    resize_bn<<<304, 256, 0, stream>>>(Vs, V, nullptr, nullptr, flag, 0);
    final_kernel<<<304, 256, 0, stream>>>(att, V, c6_b, flag, d_out);
}

// Round 4
// 1694.686 us; speedup vs baseline: 7.4399x; 7.4399x over previous
//
#include <hip/hip_runtime.h>
#include <hip/hip_bf16.h>

// ---------------------------------------------------------------------------
// up_deeplabv3Head — round 3: bf16-MFMA conv engine (16x16x32), fused taps,
// split-K via gridDim.z + fp32 atomicAdd into pre-zeroed accumulators.
// Dtype-adaptive (fp32/bf16 storage) via probe flag, as in round 2 (passed).
// Pipeline fusions kept: c6 commutes to 19-ch tail; ap = per-segment 1x1;
// GAP -> constant; d=36 conv == center tap; r2 commutes with resize.
// ---------------------------------------------------------------------------

typedef unsigned short u16;
typedef short bf16x8 __attribute__((ext_vector_type(8)));
typedef float f32x4  __attribute__((ext_vector_type(4)));

__device__ __forceinline__ float bf2f(u16 u) {
    return __uint_as_float(((unsigned int)u) << 16);
}
__device__ __forceinline__ u16 f2bf(float f) {   // round-to-nearest-even
    unsigned u = __float_as_uint(f);
    return (u16)((u + 0x7FFFu + ((u >> 16) & 1u)) >> 16);
}
// flag f32: 1 -> storage fp32, 0 -> storage bf16
__device__ __forceinline__ float loadv(const void* p, long i, int f32) {
    return f32 ? ((const float*)p)[i] : bf2f(((const u16*)p)[i]);
}
__device__ __forceinline__ u16 loadbf(const void* p, long i, int f32) {
    return f32 ? f2bf(((const float*)p)[i]) : ((const u16*)p)[i];
}

// ---------------------------------------------------------------------------
// dtype probe (round-2, verified): bf16-stored N(0,1) has ~0 large-exponent
// u16 words; fp32-stored has ~38%.
// ---------------------------------------------------------------------------
__global__ __launch_bounds__(256) void detect_kernel(
    const u16* __restrict__ c1, int* __restrict__ flag)
{
    __shared__ int cnt;
    if (threadIdx.x == 0) cnt = 0;
    __syncthreads();
    int local = 0;
    for (int i = threadIdx.x; i < 16384; i += 256) {
        u16 u = c1[i];
        if ((u & 0x7F80) >= 0x4F00) local++;
    }
    atomicAdd(&cnt, local);
    __syncthreads();
    if (threadIdx.x == 0) flag[0] = (cnt > 256) ? 1 : 0;
}

__global__ __launch_bounds__(256) void zero_kernel(float* __restrict__ p, int n)
{
    for (int g = blockIdx.x * 256 + threadIdx.x; g < n; g += gridDim.x * 256)
        p[g] = 0.f;
}

// ---------------------------------------------------------------------------
// MFMA conv: OUT[o, p] += sum_{tap,c} W[o, c, tap] * Xpad[c, p + shift(tap)]
// Tile: 64 o x 128 px per block; 4 waves; each wave: m-rows [16w,16w+16),
// 8 n-tiles of 16 px. K-split across gridDim.z (atomicAdd, OUT pre-zeroed).
// W layout: element index o*wrow + woff + c*wstride (+tap for 3x3).
// Fragments (verified layouts): A[m=lane&15][k=quad*8+j], B[k=quad*8+i][n=lane&15],
// D col=lane&15, row=quad*4+reg.
// ---------------------------------------------------------------------------
__global__ __launch_bounds__(256) void conv_mfma(
    const void* __restrict__ W, const void* __restrict__ X, float* __restrict__ OUT,
    const int* __restrict__ flag, int x_ext,
    int K, int wrow, int wstride, int woff, int taps, int d, int logIW)
{
    __shared__ __align__(16) u16 Ws[64 * 40];
    __shared__ __align__(16) u16 Xs[128 * 40];

    const int IW = 1 << logIW;
    const int NP = IW * IW;
    const int wf32 = flag[0];
    const int xf32 = x_ext ? wf32 : 1;

    const int tid = threadIdx.x;
    const int bo = blockIdx.x, bp = blockIdx.y;
    const int kcs = K / gridDim.z;
    const int kb = blockIdx.z * kcs;

    // staging roles
    const int w_o = tid >> 2, w_kg = (tid & 3) * 8;   // W: 64 o x 32 k
    const int x_p = tid >> 1, x_kg = (tid & 1) * 16;  // X: 128 p x 32 k
    const int pg  = bp * 128 + x_p;
    const int py  = pg >> logIW, px = pg & (IW - 1);
    // tile row range (tile always spans full columns since 128 >= IW)
    const int ty0 = (bp * 128) >> logIW;
    const int ty1 = ty0 + (128 >> logIW) - 1;

    const int wave = tid >> 6, lane = tid & 63;
    const int quad = lane >> 4, l15 = lane & 15;

    f32x4 acc[8];
#pragma unroll
    for (int j = 0; j < 8; j++) {
        f32x4 z = {0.f, 0.f, 0.f, 0.f};
        acc[j] = z;
    }

    const long wbase_o = (long)(bo * 64 + w_o) * wrow + woff;

    for (int kc = kb; kc < kb + kcs; kc += 32) {
        for (int t = 0; t < taps; t++) {
            int dy = 0, dx = 0, wt = 0;
            if (taps == 9) { dy = (t / 3 - 1) * d; dx = (t % 3 - 1) * d; wt = t; }
            // uniform skip: whole tile row-range OOB for this tap
            if (ty1 + dy < 0 || ty0 + dy >= IW) continue;

            // ---- stage W (64 o x 32 k, bf16, [o][k] stride 40) ----
            {
                u16 tv[8];
                if (wstride == 1) {
                    long idx = wbase_o + kc + w_kg;
                    if (wf32) {
                        float4 v0 = *(const float4*)((const float*)W + idx);
                        float4 v1 = *(const float4*)((const float*)W + idx + 4);
                        tv[0] = f2bf(v0.x); tv[1] = f2bf(v0.y);
                        tv[2] = f2bf(v0.z); tv[3] = f2bf(v0.w);
                        tv[4] = f2bf(v1.x); tv[5] = f2bf(v1.y);
                        tv[6] = f2bf(v1.z); tv[7] = f2bf(v1.w);
                    } else {
                        ushort4 v0 = *(const ushort4*)((const u16*)W + idx);
                        ushort4 v1 = *(const ushort4*)((const u16*)W + idx + 4);
                        tv[0] = v0.x; tv[1] = v0.y; tv[2] = v0.z; tv[3] = v0.w;
                        tv[4] = v1.x; tv[5] = v1.y; tv[6] = v1.z; tv[7] = v1.w;
                    }
                } else {  // stride 9 (3x3)
                    long idx = wbase_o + wt + (long)(kc + w_kg) * 9;
#pragma unroll
                    for (int i = 0; i < 8; i++)
                        tv[i] = loadbf(W, idx + (long)i * 9, wf32);
                }
                *(ushort4*)&Ws[w_o * 40 + w_kg]     = make_ushort4(tv[0], tv[1], tv[2], tv[3]);
                *(ushort4*)&Ws[w_o * 40 + w_kg + 4] = make_ushort4(tv[4], tv[5], tv[6], tv[7]);
            }
            // ---- stage X (128 p x 32 k, bf16, [p][k] stride 40, zero-pad OOB) ----
            {
                int yy = py + dy, xv = px + dx;
                bool ok = ((unsigned)yy < (unsigned)IW) && ((unsigned)xv < (unsigned)IW);
                u16 tv[16];
                if (ok) {
                    long idx = (long)(kc + x_kg) * NP + yy * IW + xv;
                    if (xf32) {
#pragma unroll
                        for (int i = 0; i < 16; i++)
                            tv[i] = f2bf(((const float*)X)[idx + (long)i * NP]);
                    } else {
#pragma unroll
                        for (int i = 0; i < 16; i++)
                            tv[i] = ((const u16*)X)[idx + (long)i * NP];
                    }
                } else {
#pragma unroll
                    for (int i = 0; i < 16; i++) tv[i] = 0;
                }
                *(ushort4*)&Xs[x_p * 40 + x_kg]      = make_ushort4(tv[0], tv[1], tv[2], tv[3]);
                *(ushort4*)&Xs[x_p * 40 + x_kg + 4]  = make_ushort4(tv[4], tv[5], tv[6], tv[7]);
                *(ushort4*)&Xs[x_p * 40 + x_kg + 8]  = make_ushort4(tv[8], tv[9], tv[10], tv[11]);
                *(ushort4*)&Xs[x_p * 40 + x_kg + 12] = make_ushort4(tv[12], tv[13], tv[14], tv[15]);
            }
            __syncthreads();
            // ---- compute: 1 A-frag, 8 B-frags, 8 MFMA per wave ----
            {
                bf16x8 a = *(const bf16x8*)&Ws[(wave * 16 + l15) * 40 + quad * 8];
#pragma unroll
                for (int j = 0; j < 8; j++) {
                    bf16x8 b = *(const bf16x8*)&Xs[(j * 16 + l15) * 40 + quad * 8];
                    acc[j] = __builtin_amdgcn_mfma_f32_16x16x32_bf16(a, b, acc[j], 0, 0, 0);
                }
            }
            __syncthreads();
        }
    }

    // ---- epilogue: atomic accumulate (split-K) ----
#pragma unroll
    for (int j = 0; j < 8; j++) {
        int pgl = bp * 128 + j * 16 + l15;
        long ob = (long)(bo * 64 + wave * 16 + quad * 4);
#pragma unroll
        for (int r = 0; r < 4; r++)
            atomicAdd(&OUT[(ob + r) * NP + pgl], acc[j][r]);
    }
}

// bn+relu in place over (C, N) f32, N = 2^logN; s,b external
__global__ __launch_bounds__(256) void ep_bnrelu(
    float* __restrict__ buf, const void* __restrict__ s, const void* __restrict__ b,
    const int* __restrict__ flag, int logN, int total)
{
    int f32 = flag[0];
    int g = blockIdx.x * 256 + threadIdx.x;
    if (g >= total) return;
    int c = g >> logN;
    float v = buf[g] * loadv(s, c, f32) + loadv(b, c, f32);
    buf[g] = fmaxf(v, 0.f);
}

// aspp epilogue: v = relu((acc + f4con[c]) * s[c] + b[c]); (512,1024)
__global__ __launch_bounds__(256) void ep_aspp(
    float* __restrict__ buf, const float* __restrict__ f4con,
    const void* __restrict__ s, const void* __restrict__ b, const int* __restrict__ flag)
{
    int f32 = flag[0];
    int g = blockIdx.x * 256 + threadIdx.x;  // 524288 exact
    int c = g >> 10;
    float v = (buf[g] + f4con[c]) * loadv(s, c, f32) + loadv(b, c, f32);
    buf[g] = fmaxf(v, 0.f);
}

// bilinear resize 32x32 -> 64x64 align_corners, optional bn+relu, (C,*) fp32 in
__global__ __launch_bounds__(256) void resize_bn(
    const float* __restrict__ in, float* __restrict__ out,
    const void* __restrict__ s, const void* __restrict__ b,
    const int* __restrict__ flag, int dobn)
{
    int g = blockIdx.x * 256 + threadIdx.x;  // C*4096 exact
    int c = g >> 12, p = g & 4095;
    int oy = p >> 6, ox = p & 63;
    const float r = 31.0f / 63.0f;
    float tyf = oy * r, txf = ox * r;
    int y0 = (int)tyf, x0 = (int)txf;
    float fy = tyf - y0, fx = txf - x0;
    int y1 = y0 + 1 > 31 ? 31 : y0 + 1;
    int x1 = x0 + 1 > 31 ? 31 : x0 + 1;
    const float* pc = in + c * 1024;
    float v00 = pc[y0 * 32 + x0], v01 = pc[y0 * 32 + x1];
    float v10 = pc[y1 * 32 + x0], v11 = pc[y1 * 32 + x1];
    float v = (1.f - fy) * ((1.f - fx) * v00 + fx * v01) +
              fy * ((1.f - fx) * v10 + fx * v11);
    if (dobn) v = fmaxf(v * loadv(s, c, flag[0]) + loadv(b, c, flag[0]), 0.f);
    out[g] = v;
}

// energy + softmax: one wave (64 lanes = 64 channels) per pixel of 64x64
__global__ __launch_bounds__(256) void attn_kernel(
    const float* __restrict__ c1r, const float* __restrict__ c2r, float* __restrict__ att)
{
    int tid = threadIdx.x;
    int p = blockIdx.x * 4 + (tid >> 6);
    int lane = tid & 63;
    int y = p >> 6, x = p & 63;
    float a = c1r[lane * 4096 + p];
    float e[9];
#pragma unroll
    for (int ky = 0; ky < 3; ky++)
#pragma unroll
        for (int kx = 0; kx < 3; kx++) {
            int yy = y + 2 * (ky - 1), xx = x + 2 * (kx - 1);
            float v = 0.f;
            if (yy >= 0 && yy < 64 && xx >= 0 && xx < 64)
                v = a * c2r[lane * 4096 + yy * 64 + xx];
#pragma unroll
            for (int off = 32; off; off >>= 1) v += __shfl_xor(v, off);
            e[ky * 3 + kx] = v;
        }
    float m = e[0];
#pragma unroll
    for (int k = 1; k < 9; k++) m = fmaxf(m, e[k]);
    float ssum = 0.f;
#pragma unroll
    for (int k = 0; k < 9; k++) ssum += __expf(e[k] - m);
    if (lane < 9) {
        float mye = e[0];
#pragma unroll
        for (int k = 1; k < 9; k++)
            if (lane == k) mye = e[k];
        att[p * 9 + lane] = __expf(mye - m) / ssum;
    }
}

// global average pool over 1024 px: one wave per channel (4096 channels)
__global__ __launch_bounds__(256) void gap_kernel(
    const void* __restrict__ x, const int* __restrict__ flag, float* __restrict__ gap)
{
    int f32 = flag[0];
    int tid = threadIdx.x;
    int c = blockIdx.x * 4 + (tid >> 6);
    int lane = tid & 63;
    long base = (long)c * 1024;
    float ssum = 0.f;
#pragma unroll
    for (int i = 0; i < 16; i++) ssum += loadv(x, base + lane + i * 64, f32);
#pragma unroll
    for (int off = 32; off; off >>= 1) ssum += __shfl_xor(ssum, off);
    if (lane == 0) gap[c] = ssum * (1.0f / 1024.0f);
}

// f4 channel vector: one wave per output channel (512)
__global__ __launch_bounds__(256) void f4_kernel(
    const void* __restrict__ w, const float* __restrict__ gap,
    const void* __restrict__ s, const void* __restrict__ b,
    const int* __restrict__ flag, float* __restrict__ f4c)
{
    int f32 = flag[0];
    int tid = threadIdx.x;
    int o = blockIdx.x * 4 + (tid >> 6);
    int lane = tid & 63;
    long base = (long)o * 4096;
    float ssum = 0.f;
#pragma unroll
    for (int i = 0; i < 64; i++)
        ssum += loadv(w, base + lane + i * 64, f32) * gap[lane + i * 64];
#pragma unroll
    for (int off = 32; off; off >>= 1) ssum += __shfl_xor(ssum, off);
    if (lane == 0) f4c[o] = fmaxf(ssum * loadv(s, o, f32) + loadv(b, o, f32), 0.f);
}

// f4con[o] = sum_c ap_w[o, 2048 + c] * f4c[c]
__global__ __launch_bounds__(256) void f4con_kernel(
    const void* __restrict__ ap_w, const float* __restrict__ f4c,
    const int* __restrict__ flag, float* __restrict__ f4con)
{
    int f32 = flag[0];
    int tid = threadIdx.x;
    int o = blockIdx.x * 4 + (tid >> 6);
    int lane = tid & 63;
    long base = (long)o * 2560 + 2048;
    float ssum = 0.f;
#pragma unroll
    for (int i = 0; i < 8; i++)
        ssum += loadv(ap_w, base + lane + i * 64, f32) * f4c[lane + i * 64];
#pragma unroll
    for (int off = 32; off; off >>= 1) ssum += __shfl_xor(ssum, off);
    if (lane == 0) f4con[o] = ssum;
}

// Vs[q,p] = sum_c c6_w[q,c] * aspp[c,p]   (19 x 1024)
__global__ __launch_bounds__(256) void vs_kernel(
    const float* __restrict__ aspp, const void* __restrict__ w,
    const int* __restrict__ flag, float* __restrict__ Vs)
{
    int f32 = flag[0];
    int p = blockIdx.x * 256 + threadIdx.x;  // grid (4, 19)
    int q = blockIdx.y;
    long wb = (long)q * 512;
    float a0 = 0.f, a1 = 0.f, a2 = 0.f, a3 = 0.f;
    for (int c = 0; c < 512; c += 4) {
        a0 = fmaf(loadv(w, wb + c + 0, f32), aspp[(c + 0) * 1024 + p], a0);
        a1 = fmaf(loadv(w, wb + c + 1, f32), aspp[(c + 1) * 1024 + p], a1);
        a2 = fmaf(loadv(w, wb + c + 2, f32), aspp[(c + 2) * 1024 + p], a2);
        a3 = fmaf(loadv(w, wb + c + 3, f32), aspp[(c + 3) * 1024 + p], a3);
    }
    Vs[q * 1024 + p] = (a0 + a1) + (a2 + a3);
}

// out[q,p] = c6_b[q] + sum_k att[p,k] * V[q, nbr_k(p)]; store dtype per flag
__global__ __launch_bounds__(256) void final_kernel(
    const float* __restrict__ att, const float* __restrict__ V,
    const void* __restrict__ bias, const int* __restrict__ flag, void* __restrict__ out)
{
    int f32 = flag[0];
    int g = blockIdx.x * 256 + threadIdx.x;  // 77824 exact (304 blocks)
    int q = g >> 12, p = g & 4095;
    int y = p >> 6, x = p & 63;
    const float* a = att + p * 9;
    const float* v = V + q * 4096;
    float acc = loadv(bias, q, f32);
#pragma unroll
    for (int ky = 0; ky < 3; ky++)
#pragma unroll
        for (int kx = 0; kx < 3; kx++) {
            int yy = y + 2 * (ky - 1), xx = x + 2 * (kx - 1);
            if (yy >= 0 && yy < 64 && xx >= 0 && xx < 64)
                acc += a[ky * 3 + kx] * v[yy * 64 + xx];
        }
    if (f32) ((float*)out)[g] = acc;
    else     ((__hip_bfloat16*)out)[g] = __float2bfloat16(acc);
}

// ---------------------------------------------------------------------------
// Host orchestration
// ---------------------------------------------------------------------------
extern "C" void kernel_launch(void* const* d_in, const int* in_sizes, int n_in,
                              void* d_out, int out_size, void* d_ws, size_t ws_size,
                              hipStream_t stream)
{
    const void* c1    = d_in[0];
    const void* c2    = d_in[1];
    const void* x     = d_in[2];
    const void* rf1_w = d_in[3];
    const void* rf1_s = d_in[4];
    const void* rf1_b = d_in[5];
    const void* rf2_w = d_in[6];
    const void* rf2_s = d_in[7];
    const void* rf2_b = d_in[8];
    const void* r2_w  = d_in[9];
    const void* r2_s  = d_in[10];
    const void* r2_b  = d_in[11];
    const void* a0_w  = d_in[12];
    const void* a0_s  = d_in[13];
    const void* a0_b  = d_in[14];
    const void* a1_w  = d_in[15];
    const void* a1_s  = d_in[16];
    const void* a1_b  = d_in[17];
    const void* a2_w  = d_in[18];
    const void* a2_s  = d_in[19];
    const void* a2_b  = d_in[20];
    const void* a3_w  = d_in[21];
    const void* a3_s  = d_in[22];
    const void* a3_b  = d_in[23];
    const void* a4_w  = d_in[24];
    const void* a4_s  = d_in[25];
    const void* a4_b  = d_in[26];
    const void* ap_w  = d_in[27];
    const void* ap_s  = d_in[28];
    const void* ap_b  = d_in[29];
    const void* c6_w  = d_in[30];
    const void* c6_b  = d_in[31];

    // ---- workspace layout (floats), ~8.2 MB; accumulators first (zeroed) ----
    float* ws    = (float*)d_ws;
    float* bufR  = ws;                 //  262144  rf1 out (64,4096)   [accum]
    float* c1r   = bufR + 262144;      //  262144  rf2 out (64,4096)   [accum]
    float* bufC  = c1r + 262144;       //   65536  r2 out (64,1024)    [accum]
    float* aspp  = bufC + 65536;       //  524288  ap out (512,1024)   [accum]
    float* tmp   = aspp + 524288;      //  524288  ASPP branch (512,1024) [accum, reused x4]
    float* c2r   = tmp + 524288;       //  262144  (64,4096)
    float* att   = c2r + 262144;       //   36864  (4096,9)
    float* gapv  = att + 36864;        //    4096
    float* f4c   = gapv + 4096;        //     512
    float* f4con = f4c + 512;          //     512
    float* Vs    = f4con + 512;        //   19456  (19,1024)
    float* V     = Vs + 19456;         //   77824  (19,4096)
    int*   flag  = (int*)(V + 77824);

    // ---- dtype probe + zero all static accumulators (bufR..aspp contiguous) ----
    detect_kernel<<<1, 256, 0, stream>>>((const u16*)c1, flag);
    zero_kernel<<<1024, 256, 0, stream>>>(ws, 1114112);

    // ---- refine(c1): two 3x3 dil-2 convs + bn_relu (IW=64, P=4096) ----
    conv_mfma<<<dim3(1, 32, 4), 256, 0, stream>>>(rf1_w, c1, bufR, flag, 1,
                                                  256, 256 * 9, 9, 0, 9, 2, 6);
    ep_bnrelu<<<1024, 256, 0, stream>>>(bufR, rf1_s, rf1_b, flag, 12, 262144);
    conv_mfma<<<dim3(1, 32, 2), 256, 0, stream>>>(rf2_w, bufR, c1r, flag, 0,
                                                  64, 64 * 9, 9, 0, 9, 2, 6);
    ep_bnrelu<<<1024, 256, 0, stream>>>(c1r, rf2_s, rf2_b, flag, 12, 262144);

    // ---- refine2: 1x1 conv on c2 (commutes with resize), then resize+bn ----
    conv_mfma<<<dim3(1, 8, 4), 256, 0, stream>>>(r2_w, c2, bufC, flag, 1,
                                                 512, 512, 1, 0, 1, 0, 5);
    resize_bn<<<1024, 256, 0, stream>>>(bufC, c2r, r2_s, r2_b, flag, 1);

    // ---- attention (energy + softmax over 9 neighbors) ----
    attn_kernel<<<1024, 256, 0, stream>>>(c1r, c2r, att);

    // ---- GAP branch ----
    gap_kernel<<<1024, 256, 0, stream>>>(x, flag, gapv);
    f4_kernel<<<128, 256, 0, stream>>>(a4_w, gapv, a4_s, a4_b, flag, f4c);
    f4con_kernel<<<128, 256, 0, stream>>>(ap_w, f4c, flag, f4con);

    // ---- ASPP branches: zero tmp -> conv -> bnrelu -> fold into aspp ----
    // seg0: 1x1
    zero_kernel<<<512, 256, 0, stream>>>(tmp, 524288);
    conv_mfma<<<dim3(8, 8, 4), 256, 0, stream>>>(a0_w, x, tmp, flag, 1,
                                                 4096, 4096, 1, 0, 1, 0, 5);
    ep_bnrelu<<<2048, 256, 0, stream>>>(tmp, a0_s, a0_b, flag, 10, 524288);
    conv_mfma<<<dim3(8, 8, 2), 256, 0, stream>>>(ap_w, tmp, aspp, flag, 0,
                                                 512, 2560, 1, 0, 1, 0, 5);
    // seg1: 3x3 d=12
    zero_kernel<<<512, 256, 0, stream>>>(tmp, 524288);
    conv_mfma<<<dim3(8, 8, 8), 256, 0, stream>>>(a1_w, x, tmp, flag, 1,
                                                 4096, 4096 * 9, 9, 0, 9, 12, 5);
    ep_bnrelu<<<2048, 256, 0, stream>>>(tmp, a1_s, a1_b, flag, 10, 524288);
    conv_mfma<<<dim3(8, 8, 2), 256, 0, stream>>>(ap_w, tmp, aspp, flag, 0,
                                                 512, 2560, 1, 512, 1, 0, 5);
    // seg2: 3x3 d=24
    zero_kernel<<<512, 256, 0, stream>>>(tmp, 524288);
    conv_mfma<<<dim3(8, 8, 8), 256, 0, stream>>>(a2_w, x, tmp, flag, 1,
                                                 4096, 4096 * 9, 9, 0, 9, 24, 5);
    ep_bnrelu<<<2048, 256, 0, stream>>>(tmp, a2_s, a2_b, flag, 10, 524288);
    conv_mfma<<<dim3(8, 8, 2), 256, 0, stream>>>(ap_w, tmp, aspp, flag, 0,
                                                 512, 2560, 1, 1024, 1, 0, 5);
    // seg3: 3x3 d=36 -> center tap only (woff=4)
    zero_kernel<<<512, 256, 0, stream>>>(tmp, 524288);
    conv_mfma<<<dim3(8, 8, 4), 256, 0, stream>>>(a3_w, x, tmp, flag, 1,
                                                 4096, 4096 * 9, 9, 4, 1, 0, 5);
    ep_bnrelu<<<2048, 256, 0, stream>>>(tmp, a3_s, a3_b, flag, 10, 524288);
    conv_mfma<<<dim3(8, 8, 2), 256, 0, stream>>>(ap_w, tmp, aspp, flag, 0,
                                                 512, 2560, 1, 1536, 1, 0, 5);
    // epilogue: add f4 constant, bn+relu
    ep_aspp<<<2048, 256, 0, stream>>>(aspp, f4con, ap_s, ap_b, flag);

    // ---- tail: c6 on 32x32, resize to 64x64, attention aggregation ----
    vs_kernel<<<dim3(4, 19), 256, 0, stream>>>(aspp, c6_w, flag, Vs);
    resize_bn<<<304, 256, 0, stream>>>(Vs, V, nullptr, nullptr, flag, 0);
    final_kernel<<<304, 256, 0, stream>>>(att, V, c6_b, flag, d_out);
}